// Round 20
// baseline (489.256 us; speedup 1.0000x reference)
//
#include <hip/hip_runtime.h>
#include <hip/hip_fp16.h>

// DEQ classifier, dx-packed 16x16x32 MFMA, row-reuse, normalized-h,
// TWO IMAGES PER BLOCK (ILP latency hiding).
// 512 blocks x 256 threads; block processes images 2b and 2b+1 in the SAME
// barrier intervals (3 barriers per iter cover BOTH images). Per-wave work
// per image = R19 exactly; doubled independent streams (accA/accB) fill the
// dependency/barrier stalls that R9-R19's 2-block TLP failed to hide
// (occupancy pinned 21.5%, ~60% stall cycles).
// LDS: two 71-row x 36-bundle buffers (8-ch f16 pixel bundles, 16 B),
// swizzle bofs(r,x)=((r*36+x)*16)^((x&8)<<1):
//   rows 0..35 zx plane (interior 2..33), rows 34..69 h plane (interior
//   36..67), rows 34/35 shared ZERO pad, row 70 = guard row (absorbs the
//   row-reuse tx=6/7 overreads; R18's NaN lesson).
// Conv as MFMA 16x16x32 with ROW-REUSE (R15-proven):
//   chunk (ty,txh): A[16 rows=(dx*8+oc)][32 k=(tx=4*txh+tg, ch)] frag;
//   ONE B-read at pixel row pr feeds output rows g=pr-ty (0<=g<8).
//   D: col=lane&15=anchor, row=(lane>>4)*4+reg  (R9-verified)
// NORMALIZED-H (R19-proven): conv1 acc held in regs across B1; h written
// normalized -> conv2 uses RAW w2 frags + plain b2; exact zero pads.
// Frag tables iteration-invariant in VGPRs (80 regs).
// launch_bounds(256,1); est ~180-220 VGPR (1 wave/SIMD -- intended: ILP not
// TLP). Tripwire: FETCH_SIZE ~7 MB; spill shows as FETCH/WRITE blowup.

typedef _Float16 half8 __attribute__((ext_vector_type(8)));
typedef float f32x4 __attribute__((ext_vector_type(4)));

#define HOFF  34                  // h-plane row offset in a buffer
#define NBUF  (71 * 36 * 4)       // 10224 dwords per image buffer (w/ guard)

__device__ __forceinline__ unsigned pk2(float a, float b) {
    __half2 h = __float22half2_rn(make_float2(a, b));
    return *reinterpret_cast<unsigned*>(&h);
}
__device__ __forceinline__ float2 up2(unsigned u) {
    __half2 h = *reinterpret_cast<__half2*>(&u);
    return __half22float2(h);
}
__device__ __forceinline__ float lrelu(float x) { return fmaxf(x, 0.01f * x); }
__device__ __forceinline__ int bofs(int r, int x) {
    return ((r * 36 + x) * 16) ^ ((x & 8) << 1);
}

// ---- prep: row-reuse A-fragments (identical to R19) ----
// ws[0..2559]    : conv1 frags, chunk c=(ty*2+txh), lane l:
//   row=l&15 (dx=row>>3, oc=row&7), tg=l>>4, tx=4*txh+tg, kx=tx-dx
//   elem pair d = ch (2d,2d+1): w1[oc][ch][ty][kx], 0 if oc>=6 or kx not in [0,5)
// ws[2560..5119] : conv2 frags from w2 (0 if oc>=5, ch>=6)
__global__ void pack_weights(const float* __restrict__ w1,
                             const float* __restrict__ w2,
                             unsigned* __restrict__ ws)
{
    int t = blockIdx.x * 256 + threadIdx.x;
    if (t < 640) {
        int c = t >> 6, l = t & 63;
        int row = l & 15, tg = l >> 4;
        int dx = row >> 3, oc = row & 7;
        int ty = c >> 1, tx = 4 * (c & 1) + tg, kx = tx - dx;
        unsigned q[4];
        #pragma unroll
        for (int d = 0; d < 4; ++d) {
            float v0 = 0.f, v1 = 0.f;
            if (oc < 6 && kx >= 0 && kx < 5) {
                v0 = w1[(oc * 8 + 2 * d) * 25 + ty * 5 + kx];
                v1 = w1[(oc * 8 + 2 * d + 1) * 25 + ty * 5 + kx];
            }
            q[d] = pk2(v0, v1);
        }
        *(uint4*)&ws[t * 4] = make_uint4(q[0], q[1], q[2], q[3]);
    } else if (t < 1280) {
        int u = t - 640;
        int c = u >> 6, l = u & 63;
        int row = l & 15, tg = l >> 4;
        int dx = row >> 3, oc = row & 7;
        int ty = c >> 1, tx = 4 * (c & 1) + tg, kx = tx - dx;
        unsigned q[4];
        #pragma unroll
        for (int d = 0; d < 4; ++d) {
            float v0 = 0.f, v1 = 0.f;
            if (oc < 5 && kx >= 0 && kx < 5) {
                if (2 * d < 6)     v0 = w2[(oc * 6 + 2 * d) * 25 + ty * 5 + kx];
                if (2 * d + 1 < 6) v1 = w2[(oc * 6 + 2 * d + 1) * 25 + ty * 5 + kx];
            }
            q[d] = pk2(v0, v1);
        }
        *(uint4*)&ws[2560 + u * 4] = make_uint4(q[0], q[1], q[2], q[3]);
    }
}

__global__ __launch_bounds__(256, 1)
void deq_kernel(const float* __restrict__ image,
                const unsigned* __restrict__ wks,
                const float* __restrict__ b1,
                const float* __restrict__ gam, const float* __restrict__ bet,
                const float* __restrict__ b2,
                const float* __restrict__ wh, const float* __restrict__ bh,
                float* __restrict__ out)
{
    __shared__ __align__(16) unsigned bufA[NBUF];
    __shared__ __align__(16) unsigned bufB[NBUF];
    __shared__ float redA[48], redB[48];

    const int n0   = blockIdx.x * 2;
    const int n1   = n0 + 1;
    const int tid  = threadIdx.x;
    const int lane = tid & 63;
    const int wid  = tid >> 6;          // 0..3: wave owns output rows wid*8..+7
    const int col  = lane & 15;         // anchor: pixels 2col, 2col+1
    const int tg   = lane >> 4;
    const int dxl  = tg >> 1;
    const int sub  = tg & 1;

    for (int p = tid; p < NBUF; p += 256) { bufA[p] = 0u; bufB[p] = 0u; }
    __syncthreads();

    {   // image -> zx bundle ch 5..7, both images (1x4 strip per thread)
        const int yy = tid >> 3, xx0 = (tid & 7) << 2;
        #pragma unroll
        for (int im = 0; im < 2; ++im) {
            const int nn = n0 + im;
            unsigned* bb = im ? bufB : bufA;
            float4 i0 = *(const float4*)&image[(nn * 3 + 0) * 1024 + yy * 32 + xx0];
            float4 i1 = *(const float4*)&image[(nn * 3 + 1) * 1024 + yy * 32 + xx0];
            float4 i2 = *(const float4*)&image[(nn * 3 + 2) * 1024 + yy * 32 + xx0];
            float a0[4] = {i0.x, i0.y, i0.z, i0.w};
            float a1[4] = {i1.x, i1.y, i1.z, i1.w};
            float a2[4] = {i2.x, i2.y, i2.z, i2.w};
            #pragma unroll
            for (int i = 0; i < 4; ++i) {
                unsigned* bp = (unsigned*)((char*)bb + bofs(yy + 2, xx0 + 2 + i));
                bp[2] = pk2(0.f, a0[i]);
                bp[3] = pk2(a1[i], a2[i]);
            }
        }
    }

    // weight A-fragments once in VGPRs
    uint4 f1[10], f2[10];
    #pragma unroll
    for (int c = 0; c < 10; ++c) {
        f1[c] = *(const uint4*)&wks[(c * 64 + lane) * 4];
        f2[c] = *(const uint4*)&wks[2560 + (c * 64 + lane) * 4];
    }

    int sx2[2];
    #pragma unroll
    for (int txh = 0; txh < 2; ++txh) {
        int x = 2 * col + 4 * txh + tg;
        sx2[txh] = (x * 16) ^ ((x & 8) << 1);
    }

    const int chb = (tg & 1) * 4;
    float b1q[4], b2q[4], gq[4], bq[4];
    #pragma unroll
    for (int r = 0; r < 4; ++r) {
        int oc = chb + r;
        b1q[r] = (oc < 6) ? b1[oc] : 0.f;
        b2q[r] = (oc < 5) ? b2[oc] : 0.f;
        gq[r]  = (oc < 6) ? gam[oc] : 0.f;
        bq[r]  = (oc < 6) ? bet[oc] : 0.f;
    }
    const f32x4 ai1 = {b1q[0], b1q[1], b1q[2], b1q[3]};
    const f32x4 ai2 = {b2q[0], b2q[1], b2q[2], b2q[3]};

    __syncthreads();

    const int ay0 = wid << 3;
    const int hwp0 = bofs(0, 2 * col + dxl + 2) + sub * 8;

    #pragma unroll 1
    for (int it = 0; it < 30; ++it) {
        // ================= conv1 on BOTH images =================
        f32x4 accA[8], accB[8];
        #pragma unroll
        for (int g = 0; g < 8; ++g) { accA[g] = ai1; accB[g] = ai1; }

        #pragma unroll
        for (int pr = 0; pr < 12; ++pr) {
            const char* rpA = (const char*)bufA + (ay0 + pr) * 576;
            const char* rpB = (const char*)bufB + (ay0 + pr) * 576;
            #pragma unroll
            for (int txh = 0; txh < 2; ++txh) {
                half8 pvA = *(const half8*)(rpA + sx2[txh]);
                half8 pvB = *(const half8*)(rpB + sx2[txh]);
                #pragma unroll
                for (int ty = 0; ty < 5; ++ty) {
                    const int g = pr - ty;
                    if (g >= 0 && g < 8) {
                        half8 wf = __builtin_bit_cast(half8, f1[ty * 2 + txh]);
                        accA[g] = __builtin_amdgcn_mfma_f32_16x16x32_f16(wf, pvA, accA[g], 0, 0, 0);
                        accB[g] = __builtin_amdgcn_mfma_f32_16x16x32_f16(wf, pvB, accB[g], 0, 0, 0);
                    }
                }
            }
        }

        // ---- leaky (in regs) + GN partial stats, both images ----
        float psA_lo = 0.f, psA_hi = 0.f, pqA_lo = 0.f, pqA_hi = 0.f;
        float psB_lo = 0.f, psB_hi = 0.f, pqB_lo = 0.f, pqB_hi = 0.f;
        #pragma unroll
        for (int g = 0; g < 8; ++g) {
            float a0 = lrelu(accA[g][0]), a1 = lrelu(accA[g][1]);
            float a2 = lrelu(accA[g][2]), a3 = lrelu(accA[g][3]);
            accA[g][0] = a0; accA[g][1] = a1; accA[g][2] = a2; accA[g][3] = a3;
            psA_lo += a0 + a1;  pqA_lo = fmaf(a0, a0, fmaf(a1, a1, pqA_lo));
            psA_hi += a2 + a3;  pqA_hi = fmaf(a2, a2, fmaf(a3, a3, pqA_hi));
            float c0 = lrelu(accB[g][0]), c1 = lrelu(accB[g][1]);
            float c2 = lrelu(accB[g][2]), c3 = lrelu(accB[g][3]);
            accB[g][0] = c0; accB[g][1] = c1; accB[g][2] = c2; accB[g][3] = c3;
            psB_lo += c0 + c1;  pqB_lo = fmaf(c0, c0, fmaf(c1, c1, pqB_lo));
            psB_hi += c2 + c3;  pqB_hi = fmaf(c2, c2, fmaf(c3, c3, pqB_hi));
        }

        #pragma unroll
        for (int m = 1; m <= 8; m <<= 1) {
            psA_lo += __shfl_xor(psA_lo, m); psA_hi += __shfl_xor(psA_hi, m);
            pqA_lo += __shfl_xor(pqA_lo, m); pqA_hi += __shfl_xor(pqA_hi, m);
            psB_lo += __shfl_xor(psB_lo, m); psB_hi += __shfl_xor(psB_hi, m);
            pqB_lo += __shfl_xor(pqB_lo, m); pqB_hi += __shfl_xor(pqB_hi, m);
        }
        psA_lo += __shfl_xor(psA_lo, 32); psA_hi += __shfl_xor(psA_hi, 32);
        pqA_lo += __shfl_xor(pqA_lo, 32); pqA_hi += __shfl_xor(pqA_hi, 32);
        psB_lo += __shfl_xor(psB_lo, 32); psB_hi += __shfl_xor(psB_hi, 32);
        pqB_lo += __shfl_xor(pqB_lo, 32); pqB_hi += __shfl_xor(pqB_hi, 32);
        if (lane == 0) {
            redA[wid * 8 + 0] = psA_lo; redA[wid * 8 + 1] = psA_hi;
            redA[wid * 8 + 4] = pqA_lo; redA[wid * 8 + 5] = pqA_hi;
            redB[wid * 8 + 0] = psB_lo; redB[wid * 8 + 1] = psB_hi;
            redB[wid * 8 + 4] = pqB_lo; redB[wid * 8 + 5] = pqB_hi;
        }
        if (lane == 16) {
            redA[wid * 8 + 2] = psA_lo; redA[wid * 8 + 6] = pqA_lo;
            redB[wid * 8 + 2] = psB_lo; redB[wid * 8 + 6] = pqB_lo;
        }
        __syncthreads();                               // B1

        // ---- GN folds (cheap, all threads) ----
        float scqA[4], shqA[4], scqB[4], shqB[4];
        {
            float invm[3], meanm[3];
            #pragma unroll
            for (int g3 = 0; g3 < 3; ++g3) {
                float s = 0.f, q = 0.f;
                #pragma unroll
                for (int w = 0; w < 4; ++w) { s += redA[w * 8 + g3]; q += redA[w * 8 + 4 + g3]; }
                float mean = s * (1.f / 2048.f);
                float var  = q * (1.f / 2048.f) - mean * mean;
                invm[g3]  = rsqrtf(var + 1e-5f);
                meanm[g3] = mean;
            }
            #pragma unroll
            for (int r = 0; r < 4; ++r) {
                int oc = chb + r;
                float inv  = (oc < 6) ? invm[oc >> 1]  : 0.f;
                float mean = (oc < 6) ? meanm[oc >> 1] : 0.f;
                scqA[r] = inv * gq[r];
                shqA[r] = bq[r] - mean * scqA[r];
            }
        }
        {
            float invm[3], meanm[3];
            #pragma unroll
            for (int g3 = 0; g3 < 3; ++g3) {
                float s = 0.f, q = 0.f;
                #pragma unroll
                for (int w = 0; w < 4; ++w) { s += redB[w * 8 + g3]; q += redB[w * 8 + 4 + g3]; }
                float mean = s * (1.f / 2048.f);
                float var  = q * (1.f / 2048.f) - mean * mean;
                invm[g3]  = rsqrtf(var + 1e-5f);
                meanm[g3] = mean;
            }
            #pragma unroll
            for (int r = 0; r < 4; ++r) {
                int oc = chb + r;
                float inv  = (oc < 6) ? invm[oc >> 1]  : 0.f;
                float mean = (oc < 6) ? meanm[oc >> 1] : 0.f;
                scqB[r] = inv * gq[r];
                shqB[r] = bq[r] - mean * scqB[r];
            }
        }

        // ---- write NORMALIZED h, both images ----
        #pragma unroll
        for (int g = 0; g < 8; ++g) {
            float h0 = fmaf(accA[g][0], scqA[0], shqA[0]);
            float h1 = fmaf(accA[g][1], scqA[1], shqA[1]);
            float h2 = fmaf(accA[g][2], scqA[2], shqA[2]);
            float h3 = fmaf(accA[g][3], scqA[3], shqA[3]);
            char* wpA = (char*)bufA + (ay0 + g + 2 + HOFF) * 576 + hwp0;
            *(uint2*)wpA = make_uint2(pk2(h0, h1), pk2(h2, h3));
            float k0 = fmaf(accB[g][0], scqB[0], shqB[0]);
            float k1 = fmaf(accB[g][1], scqB[1], shqB[1]);
            float k2 = fmaf(accB[g][2], scqB[2], shqB[2]);
            float k3 = fmaf(accB[g][3], scqB[3], shqB[3]);
            char* wpB = (char*)bufB + (ay0 + g + 2 + HOFF) * 576 + hwp0;
            *(uint2*)wpB = make_uint2(pk2(k0, k1), pk2(k2, k3));
        }
        __syncthreads();                               // B2

        // ================= conv2 on BOTH images =================
        #pragma unroll
        for (int g = 0; g < 8; ++g) { accA[g] = ai2; accB[g] = ai2; }

        #pragma unroll
        for (int pr = 0; pr < 12; ++pr) {
            const char* rpA = (const char*)bufA + (HOFF + ay0 + pr) * 576;
            const char* rpB = (const char*)bufB + (HOFF + ay0 + pr) * 576;
            #pragma unroll
            for (int txh = 0; txh < 2; ++txh) {
                half8 pvA = *(const half8*)(rpA + sx2[txh]);
                half8 pvB = *(const half8*)(rpB + sx2[txh]);
                #pragma unroll
                for (int ty = 0; ty < 5; ++ty) {
                    const int g = pr - ty;
                    if (g >= 0 && g < 8) {
                        half8 wf = __builtin_bit_cast(half8, f2[ty * 2 + txh]);
                        accA[g] = __builtin_amdgcn_mfma_f32_16x16x32_f16(wf, pvA, accA[g], 0, 0, 0);
                        accB[g] = __builtin_amdgcn_mfma_f32_16x16x32_f16(wf, pvB, accB[g], 0, 0, 0);
                    }
                }
            }
        }

        // ---- leaky + damped z RMW, both images ----
        #pragma unroll
        for (int g = 0; g < 8; ++g) {
            char* zpA = (char*)bufA + bofs(ay0 + g + 2, 2 * col + dxl + 2);
            char* zpB = (char*)bufB + bofs(ay0 + g + 2, 2 * col + dxl + 2);
            if (sub == 0) {
                uint2 za = *(uint2*)zpA;
                float2 a0 = up2(za.x), a1 = up2(za.y);
                *(uint2*)zpA = make_uint2(
                    pk2(0.5f * a0.x + 0.5f * lrelu(accA[g][0]),
                        0.5f * a0.y + 0.5f * lrelu(accA[g][1])),
                    pk2(0.5f * a1.x + 0.5f * lrelu(accA[g][2]),
                        0.5f * a1.y + 0.5f * lrelu(accA[g][3])));
                uint2 zb = *(uint2*)zpB;
                float2 c0 = up2(zb.x), c1 = up2(zb.y);
                *(uint2*)zpB = make_uint2(
                    pk2(0.5f * c0.x + 0.5f * lrelu(accB[g][0]),
                        0.5f * c0.y + 0.5f * lrelu(accB[g][1])),
                    pk2(0.5f * c1.x + 0.5f * lrelu(accB[g][2]),
                        0.5f * c1.y + 0.5f * lrelu(accB[g][3])));
            } else {
                _Float16* pa = (_Float16*)(zpA + 8);
                pa[0] = (_Float16)(0.5f * (float)pa[0] + 0.5f * lrelu(accA[g][0]));
                _Float16* pb = (_Float16*)(zpB + 8);
                pb[0] = (_Float16)(0.5f * (float)pb[0] + 0.5f * lrelu(accB[g][0]));
            }
        }
        __syncthreads();                               // B3
    }

    // ================= head: both images =================
    {
        const int yy = tid >> 3, xx0 = (tid & 7) << 2;
        #pragma unroll 1
        for (int im = 0; im < 2; ++im) {
            const unsigned* bb = im ? bufB : bufA;
            float zf[5][4];
            #pragma unroll
            for (int i = 0; i < 4; ++i) {
                const unsigned* bp = (const unsigned*)((const char*)bb + bofs(yy + 2, xx0 + 2 + i));
                float2 f0 = up2(bp[0]), fb = up2(bp[1]), fc = up2(bp[2]);
                zf[0][i] = f0.x; zf[1][i] = f0.y; zf[2][i] = fb.x; zf[3][i] = fb.y; zf[4][i] = fc.x;
            }
            float ho[10];
            #pragma unroll
            for (int o = 0; o < 10; ++o) ho[o] = 0.f;
            #pragma unroll
            for (int c = 0; c < 5; ++c) {
                #pragma unroll
                for (int o = 0; o < 10; ++o) {
                    float4 wv = *(const float4*)&wh[(o * 5 + c) * 1024 + yy * 32 + xx0];
                    ho[o] = fmaf(zf[c][0], wv.x, ho[o]);
                    ho[o] = fmaf(zf[c][1], wv.y, ho[o]);
                    ho[o] = fmaf(zf[c][2], wv.z, ho[o]);
                    ho[o] = fmaf(zf[c][3], wv.w, ho[o]);
                }
            }
            #pragma unroll
            for (int m = 1; m < 64; m <<= 1) {
                #pragma unroll
                for (int o = 0; o < 10; ++o) ho[o] += __shfl_xor(ho[o], m);
            }
            float* rr = im ? redB : redA;
            if (lane == 0) {
                #pragma unroll
                for (int o = 0; o < 10; ++o) rr[wid * 10 + o] = ho[o];
            }
        }
    }
    __syncthreads();
    if (tid < 10) {
        out[n0 * 10 + tid] = redA[tid] + redA[10 + tid] + redA[20 + tid] + redA[30 + tid] + bh[tid];
        out[n1 * 10 + tid] = redB[tid] + redB[10 + tid] + redB[20 + tid] + redB[30 + tid] + bh[tid];
    }
}

extern "C" void kernel_launch(void* const* d_in, const int* in_sizes, int n_in,
                              void* d_out, int out_size, void* d_ws, size_t ws_size,
                              hipStream_t stream) {
    const float* image = (const float*)d_in[0];
    const float* w1    = (const float*)d_in[1];
    const float* b1    = (const float*)d_in[2];
    const float* gam   = (const float*)d_in[3];
    const float* bet   = (const float*)d_in[4];
    const float* w2    = (const float*)d_in[5];
    const float* b2    = (const float*)d_in[6];
    const float* wh    = (const float*)d_in[7];
    const float* bh    = (const float*)d_in[8];
    float* out = (float*)d_out;
    unsigned* ws = (unsigned*)d_ws;

    pack_weights<<<5, 256, 0, stream>>>(w1, w2, ws);

    const int N = in_sizes[0] / (3 * 32 * 32);   // 1024 images
    deq_kernel<<<N / 2, 256, 0, stream>>>(image, ws, b1, gam, bet, b2, wh, bh, out);
}

// Round 21
// 390.466 us; speedup vs baseline: 1.2530x; 1.2530x over previous
//
#include <hip/hip_runtime.h>
#include <hip/hip_fp16.h>

// DEQ classifier, dx-packed 16x16x32 MFMA, row-reuse, TWO-BARRIER scheme.
// One block per image (1024 x 256 threads, 4 waves). Key idea: eliminate the
// h-visibility barrier (B2) by making each wave self-sufficient:
//   - conv1 computes its 8 output rows PLUS 4 halo rows redundantly
//     (acc[12], uniform j=0..11 -- compile-time indices, rule #20)
//   - h written UNNORMALIZED pre-B1 into a PRIVATE per-wave 12-row region
//   - after B1 (stats): fold -> pads(-sh/sc), bias2' = b2+S2*sh, w2*sc --
//     all OWN-WAVE writes (R9-verified exact GN folding semantics)
//   - conv2 reads only its own region -> NO barrier between fold and conv2
// Barriers/iter: B1 (stats) + B3 (z halo) = 2  (was 3).
// LDS carve (dwords):
//   [0,5760)       z ext plane: 40 rows x 36 bundles (8-ch f16, 16 B);
//                  interior rows 4..35 (EXTENDED 4-row v-pads so halo conv1
//                  reads stay in-plane for all waves), x-pads cols 0,1,34,35
//   [5760,12672)   4 per-wave h regions, 12 rows x 36 bundles each
//   [12672,12816)  guard row (absorbs tx=6/7 overreads; R18 NaN lesson)
//   [12816,15376)  wl1 conv1 frags   [15376,17936) wl2 conv2 frags
// swizzle swz(x)=(x*16)^((x&8)<<1), row byte stride 576 (R9-proven bijective).
// Conv MFMA 16x16x32 row-reuse: chunk (ty,txh): A=weights frag, ONE B-read
// at pixel row feeds up to 5 outputs. D: col=lane&15, row=(lane>>4)*4+reg.
// Frag tables in LDS, loaded per section (keeps VGPR<=128 -> 2 blocks/CU;
// R20 proved 2-block TLP is load-bearing).
// Tripwire: FETCH_SIZE ~7 MB; spill shows as FETCH/WRITE blowup.

typedef _Float16 half8 __attribute__((ext_vector_type(8)));
typedef float f32x4 __attribute__((ext_vector_type(4)));

#define REG_DW  5760
#define GRD_DW  12672
#define WL1_DW  12816
#define WL2_DW  15376
#define NLDS_DW 17936

__device__ __forceinline__ unsigned pk2(float a, float b) {
    __half2 h = __float22half2_rn(make_float2(a, b));
    return *reinterpret_cast<unsigned*>(&h);
}
__device__ __forceinline__ float2 up2(unsigned u) {
    __half2 h = *reinterpret_cast<__half2*>(&u);
    return __half22float2(h);
}
__device__ __forceinline__ unsigned hmul2(unsigned a, unsigned b) {
    __half2 r = __hmul2(*reinterpret_cast<__half2*>(&a), *reinterpret_cast<__half2*>(&b));
    return *reinterpret_cast<unsigned*>(&r);
}
__device__ __forceinline__ float lrelu(float x) { return fmaxf(x, 0.01f * x); }
__device__ __forceinline__ int swz(int x) { return (x * 16) ^ ((x & 8) << 1); }

// ---- prep: row-reuse A-fragments + S2 tap-sum table ----
// ws[0..2559]    : conv1 frags, chunk c=(ty*2+txh), lane l:
//   row=l&15 (dx=row>>3, oc=row&7), tg=l>>4, tx=4*txh+tg, kx=tx-dx
//   elem pair d = ch (2d,2d+1): w1[oc][ch][ty][kx], 0 if oc>=6 or kx not in [0,5)
// ws[2560..5119] : conv2 frags from w2 (0 if oc>=5, ch>=6)
// ws[5120..5149] : S2[oc][ch] = sum_tap w2[oc][ch][tap]  (f32)
__global__ void pack_weights(const float* __restrict__ w1,
                             const float* __restrict__ w2,
                             unsigned* __restrict__ ws)
{
    int t = blockIdx.x * 256 + threadIdx.x;
    if (t < 640) {
        int c = t >> 6, l = t & 63;
        int row = l & 15, tg = l >> 4;
        int dx = row >> 3, oc = row & 7;
        int ty = c >> 1, tx = 4 * (c & 1) + tg, kx = tx - dx;
        unsigned q[4];
        #pragma unroll
        for (int d = 0; d < 4; ++d) {
            float v0 = 0.f, v1 = 0.f;
            if (oc < 6 && kx >= 0 && kx < 5) {
                v0 = w1[(oc * 8 + 2 * d) * 25 + ty * 5 + kx];
                v1 = w1[(oc * 8 + 2 * d + 1) * 25 + ty * 5 + kx];
            }
            q[d] = pk2(v0, v1);
        }
        *(uint4*)&ws[t * 4] = make_uint4(q[0], q[1], q[2], q[3]);
    } else if (t < 1280) {
        int u = t - 640;
        int c = u >> 6, l = u & 63;
        int row = l & 15, tg = l >> 4;
        int dx = row >> 3, oc = row & 7;
        int ty = c >> 1, tx = 4 * (c & 1) + tg, kx = tx - dx;
        unsigned q[4];
        #pragma unroll
        for (int d = 0; d < 4; ++d) {
            float v0 = 0.f, v1 = 0.f;
            if (oc < 5 && kx >= 0 && kx < 5) {
                if (2 * d < 6)     v0 = w2[(oc * 6 + 2 * d) * 25 + ty * 5 + kx];
                if (2 * d + 1 < 6) v1 = w2[(oc * 6 + 2 * d + 1) * 25 + ty * 5 + kx];
            }
            q[d] = pk2(v0, v1);
        }
        *(uint4*)&ws[2560 + u * 4] = make_uint4(q[0], q[1], q[2], q[3]);
    } else if (t < 1310) {
        int idx = t - 1280;
        int oc = idx / 6, ch = idx % 6;
        float s = 0.f;
        for (int tap = 0; tap < 25; ++tap) s += w2[(oc * 6 + ch) * 25 + tap];
        ((float*)ws)[5120 + idx] = s;
    }
}

__global__ __launch_bounds__(256, 1)
void deq_kernel(const float* __restrict__ image,
                const unsigned* __restrict__ wks,
                const float* __restrict__ b1,
                const float* __restrict__ gam, const float* __restrict__ bet,
                const float* __restrict__ b2,
                const float* __restrict__ wh, const float* __restrict__ bh,
                float* __restrict__ out)
{
    __shared__ __align__(16) unsigned lds[NLDS_DW];
    __shared__ float red[48];
    __shared__ float s2s[32];

    const int n    = blockIdx.x;
    const int tid  = threadIdx.x;
    const int lane = tid & 63;
    const int wid  = tid >> 6;          // 0..3: wave owns output rows wid*8..+7
    const int col  = lane & 15;
    const int tg   = lane >> 4;
    const int dxl  = tg >> 1;
    const int sub  = tg & 1;

    // zero z plane + regions + guard
    for (int p = tid; p < GRD_DW + 144; p += 256) lds[p] = 0u;
    // stage frag tables
    for (int p = tid; p < 2560; p += 256) {
        lds[WL1_DW + p] = wks[p];
        lds[WL2_DW + p] = wks[2560 + p];
    }
    if (tid < 30) s2s[tid] = ((const float*)wks)[5120 + tid];
    __syncthreads();

    {   // image -> z ext plane ch 5..7 (interior rows at +4)
        const int yy = tid >> 3, xx0 = (tid & 7) << 2;
        float4 i0 = *(const float4*)&image[(n * 3 + 0) * 1024 + yy * 32 + xx0];
        float4 i1 = *(const float4*)&image[(n * 3 + 1) * 1024 + yy * 32 + xx0];
        float4 i2 = *(const float4*)&image[(n * 3 + 2) * 1024 + yy * 32 + xx0];
        float a0[4] = {i0.x, i0.y, i0.z, i0.w};
        float a1[4] = {i1.x, i1.y, i1.z, i1.w};
        float a2[4] = {i2.x, i2.y, i2.z, i2.w};
        #pragma unroll
        for (int i = 0; i < 4; ++i) {
            unsigned* bp = (unsigned*)((char*)lds + (yy + 4) * 576 + swz(xx0 + 2 + i));
            bp[2] = pk2(0.f, a0[i]);
            bp[3] = pk2(a1[i], a2[i]);
        }
    }

    int sx2[2];
    #pragma unroll
    for (int txh = 0; txh < 2; ++txh)
        sx2[txh] = swz(2 * col + 4 * txh + tg);

    float b1q[4], b2q[4];
    #pragma unroll
    for (int r = 0; r < 4; ++r) {
        int oc = (tg * 4 + r) & 7;
        b1q[r] = (oc < 6) ? b1[oc] : 0.f;
        b2q[r] = (oc < 5) ? b2[oc] : 0.f;
    }
    const f32x4 ai1 = {b1q[0], b1q[1], b1q[2], b1q[3]};

    __syncthreads();

    char* const regb = (char*)lds + REG_DW * 4 + wid * 6912;  // own h region
    const int ay0 = wid << 3;
    const int hwp0 = swz(2 * col + dxl + 2) + sub * 8;
    const int wlo = lane << 2;

    #pragma unroll 1
    for (int it = 0; it < 30; ++it) {
        // ========== conv1: 12 output rows (8 own + 4 halo), 32 B-reads ==========
        uint4 f1[10];
        #pragma unroll
        for (int c = 0; c < 10; ++c)
            f1[c] = *(const uint4*)&lds[WL1_DW + c * 256 + wlo];

        f32x4 acc[12];
        #pragma unroll
        for (int j = 0; j < 12; ++j) acc[j] = ai1;

        #pragma unroll
        for (int u = 0; u < 16; ++u) {
            const char* rowp = (const char*)lds + (ay0 + u) * 576;
            #pragma unroll
            for (int txh = 0; txh < 2; ++txh) {
                half8 pv = *(const half8*)(rowp + sx2[txh]);
                #pragma unroll
                for (int ty = 0; ty < 5; ++ty) {
                    const int j = u - ty;
                    if (j >= 0 && j < 12)
                        acc[j] = __builtin_amdgcn_mfma_f32_16x16x32_f16(
                            __builtin_bit_cast(half8, f1[ty * 2 + txh]), pv, acc[j], 0, 0, 0);
                }
            }
        }

        // ---- leaky + UNNORMALIZED h store to own region + stats (own rows) ----
        float ps_lo = 0.f, ps_hi = 0.f, pq_lo = 0.f, pq_hi = 0.f;
        #pragma unroll
        for (int j = 0; j < 12; ++j) {
            float h0 = lrelu(acc[j][0]), h1 = lrelu(acc[j][1]);
            float h2 = lrelu(acc[j][2]), h3 = lrelu(acc[j][3]);
            if (j >= 2 && j <= 9) {
                ps_lo += h0 + h1;  pq_lo = fmaf(h0, h0, fmaf(h1, h1, pq_lo));
                ps_hi += h2 + h3;  pq_hi = fmaf(h2, h2, fmaf(h3, h3, pq_hi));
            }
            *(uint2*)(regb + j * 576 + hwp0) = make_uint2(pk2(h0, h1), pk2(h2, h3));
        }

        #pragma unroll
        for (int m = 1; m <= 8; m <<= 1) {
            ps_lo += __shfl_xor(ps_lo, m); ps_hi += __shfl_xor(ps_hi, m);
            pq_lo += __shfl_xor(pq_lo, m); pq_hi += __shfl_xor(pq_hi, m);
        }
        ps_lo += __shfl_xor(ps_lo, 32); ps_hi += __shfl_xor(ps_hi, 32);
        pq_lo += __shfl_xor(pq_lo, 32); pq_hi += __shfl_xor(pq_hi, 32);
        if (lane == 0)  { red[wid * 8 + 0] = ps_lo; red[wid * 8 + 1] = ps_hi;
                          red[wid * 8 + 4] = pq_lo; red[wid * 8 + 5] = pq_hi; }
        if (lane == 16) { red[wid * 8 + 2] = ps_lo; red[wid * 8 + 6] = pq_lo; }
        __syncthreads();                               // B1 (only cross-wave point #1)

        // ---- GN fold (all threads, full 6 channels) ----
        float scv[6], shv[6];
        #pragma unroll
        for (int g3 = 0; g3 < 3; ++g3) {
            float s = 0.f, q = 0.f;
            #pragma unroll
            for (int w = 0; w < 4; ++w) { s += red[w * 8 + g3]; q += red[w * 8 + 4 + g3]; }
            float mean = s * (1.f / 2048.f);
            float var  = q * (1.f / 2048.f) - mean * mean;
            float inv  = rsqrtf(var + 1e-5f);
            #pragma unroll
            for (int k = 0; k < 2; ++k) {
                int c = 2 * g3 + k;
                scv[c] = inv * gam[c];
                shv[c] = bet[c] - mean * scv[c];
            }
        }
        f32x4 ai2;
        #pragma unroll
        for (int r = 0; r < 4; ++r) {
            int ocr = (tg * 4 + r) & 7;
            int base = (ocr < 5) ? ocr * 6 : 0;
            float db = 0.f;
            #pragma unroll
            for (int ch = 0; ch < 6; ++ch) db = fmaf(s2s[base + ch], shv[ch], db);
            ai2[r] = b2q[r] + ((ocr < 5) ? db : 0.f);
        }
        unsigned sp0 = pk2(scv[0], scv[1]), sp1 = pk2(scv[2], scv[3]), sp2 = pk2(scv[4], scv[5]);

        // ---- own-region pads (-sh/sc): x-pads all rows; edge waves: halo rows ----
        {
            float ph[6];
            #pragma unroll
            for (int c = 0; c < 6; ++c) {
                float rs = (fabsf(scv[c]) > 1e-20f) ? 1.f / scv[c] : 0.f;
                ph[c] = -shv[c] * rs;
            }
            uint4 padq = make_uint4(pk2(ph[0], ph[1]), pk2(ph[2], ph[3]), pk2(ph[4], ph[5]), 0u);
            if (lane < 48) {
                int rr = lane >> 2, c4 = lane & 3;
                int cc = (c4 < 2) ? c4 : c4 + 32;
                *(uint4*)(regb + rr * 576 + swz(cc)) = padq;
            }
            if (wid == 0) {          // halo rows j=0,1 (image rows -2,-1): pad
                #pragma unroll 1
                for (int k = lane; k < 72; k += 64)
                    *(uint4*)(regb + (k / 36) * 576 + swz(k % 36)) = padq;
            }
            if (wid == 3) {          // halo rows j=10,11 (image rows 32,33): pad
                #pragma unroll 1
                for (int k = lane; k < 72; k += 64)
                    *(uint4*)(regb + (10 + k / 36) * 576 + swz(k % 36)) = padq;
            }
        }
        asm volatile("s_waitcnt lgkmcnt(0)" ::: "memory");   // own writes visible

        // ========== conv2: own region only, scaled frags, folded bias ==========
        uint4 f2[10];
        #pragma unroll
        for (int c = 0; c < 10; ++c) {
            uint4 wr = *(const uint4*)&lds[WL2_DW + c * 256 + wlo];
            f2[c].x = hmul2(wr.x, sp0);
            f2[c].y = hmul2(wr.y, sp1);
            f2[c].z = hmul2(wr.z, sp2);
            f2[c].w = 0u;
        }
        f32x4 a2c[8];
        #pragma unroll
        for (int g = 0; g < 8; ++g) a2c[g] = ai2;

        #pragma unroll
        for (int rr = 0; rr < 12; ++rr) {
            const char* rowp = regb + rr * 576;
            #pragma unroll
            for (int txh = 0; txh < 2; ++txh) {
                half8 pv = *(const half8*)(rowp + sx2[txh]);
                #pragma unroll
                for (int ty = 0; ty < 5; ++ty) {
                    const int g = rr - ty;
                    if (g >= 0 && g < 8)
                        a2c[g] = __builtin_amdgcn_mfma_f32_16x16x32_f16(
                            __builtin_bit_cast(half8, f2[ty * 2 + txh]), pv, a2c[g], 0, 0, 0);
                }
            }
        }

        // ---- leaky + damped z RMW (ext plane rows ay0+g+4) ----
        #pragma unroll
        for (int g = 0; g < 8; ++g) {
            char* zp = (char*)lds + (ay0 + g + 4) * 576 + swz(2 * col + dxl + 2);
            if (sub == 0) {
                uint2 zo = *(uint2*)zp;
                float2 za = up2(zo.x), zc = up2(zo.y);
                float z0 = 0.5f * za.x + 0.5f * lrelu(a2c[g][0]);
                float z1 = 0.5f * za.y + 0.5f * lrelu(a2c[g][1]);
                float z2 = 0.5f * zc.x + 0.5f * lrelu(a2c[g][2]);
                float z3 = 0.5f * zc.y + 0.5f * lrelu(a2c[g][3]);
                *(uint2*)zp = make_uint2(pk2(z0, z1), pk2(z2, z3));
            } else {
                _Float16* pz = (_Float16*)(zp + 8);
                float z4 = 0.5f * (float)pz[0] + 0.5f * lrelu(a2c[g][0]);
                pz[0] = (_Float16)z4;
            }
        }
        __syncthreads();                               // B3 (cross-wave point #2: z halo)
    }

    // ================= head: out[o] = <z, wh[o]> + bh[o] =================
    {
        const int yy = tid >> 3, xx0 = (tid & 7) << 2;
        float zf[5][4];
        #pragma unroll
        for (int i = 0; i < 4; ++i) {
            const unsigned* bp = (const unsigned*)((const char*)lds + (yy + 4) * 576 + swz(xx0 + 2 + i));
            float2 f0 = up2(bp[0]), fb = up2(bp[1]), fc = up2(bp[2]);
            zf[0][i] = f0.x; zf[1][i] = f0.y; zf[2][i] = fb.x; zf[3][i] = fb.y; zf[4][i] = fc.x;
        }
        float ho[10];
        #pragma unroll
        for (int o = 0; o < 10; ++o) ho[o] = 0.f;
        #pragma unroll
        for (int c = 0; c < 5; ++c) {
            #pragma unroll
            for (int o = 0; o < 10; ++o) {
                float4 wv = *(const float4*)&wh[(o * 5 + c) * 1024 + yy * 32 + xx0];
                ho[o] = fmaf(zf[c][0], wv.x, ho[o]);
                ho[o] = fmaf(zf[c][1], wv.y, ho[o]);
                ho[o] = fmaf(zf[c][2], wv.z, ho[o]);
                ho[o] = fmaf(zf[c][3], wv.w, ho[o]);
            }
        }
        #pragma unroll
        for (int m = 1; m < 64; m <<= 1) {
            #pragma unroll
            for (int o = 0; o < 10; ++o) ho[o] += __shfl_xor(ho[o], m);
        }
        if (lane == 0) {
            #pragma unroll
            for (int o = 0; o < 10; ++o) red[wid * 10 + o] = ho[o];
        }
    }
    __syncthreads();
    if (tid < 10)
        out[n * 10 + tid] = red[tid] + red[10 + tid] + red[20 + tid] + red[30 + tid] + bh[tid];
}

extern "C" void kernel_launch(void* const* d_in, const int* in_sizes, int n_in,
                              void* d_out, int out_size, void* d_ws, size_t ws_size,
                              hipStream_t stream) {
    const float* image = (const float*)d_in[0];
    const float* w1    = (const float*)d_in[1];
    const float* b1    = (const float*)d_in[2];
    const float* gam   = (const float*)d_in[3];
    const float* bet   = (const float*)d_in[4];
    const float* w2    = (const float*)d_in[5];
    const float* b2    = (const float*)d_in[6];
    const float* wh    = (const float*)d_in[7];
    const float* bh    = (const float*)d_in[8];
    float* out = (float*)d_out;
    unsigned* ws = (unsigned*)d_ws;

    pack_weights<<<6, 256, 0, stream>>>(w1, w2, ws);

    const int N = in_sizes[0] / (3 * 32 * 32);   // 1024 images
    deq_kernel<<<N, 256, 0, stream>>>(image, ws, b1, gam, bet, b2, wh, bh, out);
}

// Round 22
// 335.764 us; speedup vs baseline: 1.4571x; 1.1629x over previous
//
#include <hip/hip_runtime.h>
#include <hip/hip_fp16.h>

// DEQ classifier, dx-packed 16x16x32 MFMA, row-reuse, ONE-FOLD-BARRIER scheme.
// One block per image (1024 x 256 threads, 4 waves; wave owns 8 output rows).
// KEY: h is written UNNORMALIZED before B1, so ONE barrier publishes h AND
// the GN stats. Conv2 absorbs normalization in its A-operand:
//   - h bundle ch6 = INDICATOR (f16 1.0 interior, 0 pads; set once at init;
//     sub==1 h-writes touch only dword 2, so the indicator survives)
//   - post-fold frag: dwords 0-2 = w2*sc (hmul2, R9-verified), dword 3 =
//     pk2(padw,0) with padw = sum_ch w2[oc][ch][tap]*sh[ch]
//   conv2 = sum w2*sc*h_un + padw*ind = exact normalized conv; pads exact.
//   -> B2 deleted (2 barriers/iter), no pad-rewrite, no S2 table, plain b2.
// LDS carve (dwords):
//   [0,10224)       71-row x 36-bundle buffer (8-ch f16 bundles, 16 B):
//     rows 0..35 zx plane (interior 2..33), rows 34..69 h plane (interior
//     36..67), rows 34/35 shared ZERO pad, row 70 guard (R18 NaN lesson).
//   [10224,12784)   wl1 conv1 frags   [12784,15344) wl2 conv2 frags (raw)
// swizzle swz(x)=(x*16)^((x&8)<<1), row stride 576 B (bijective, R9-proven).
// Conv MFMA 16x16x32 row-reuse (R15): chunk (ty,txh) frag; ONE B-read per
// pixel row feeds outputs g=pr-ty. D: col=lane&15, row=(lane>>4)*4+reg.
// Frag tables loaded per-phase from LDS (keeps VGPR<=128 -> 2 blocks/CU;
// R20 proved the 2-block TLP is load-bearing).
// Tripwire: FETCH_SIZE ~7 MB; spill shows as FETCH/WRITE blowup.

typedef _Float16 half8 __attribute__((ext_vector_type(8)));
typedef float f32x4 __attribute__((ext_vector_type(4)));

#define HOFF   34
#define NBUF   (71 * 36 * 4)      // 10224 dwords incl guard row
#define WL1_DW 10224
#define WL2_DW 12784
#define NLDS   15344

__device__ __forceinline__ unsigned pk2(float a, float b) {
    __half2 h = __float22half2_rn(make_float2(a, b));
    return *reinterpret_cast<unsigned*>(&h);
}
__device__ __forceinline__ float2 up2(unsigned u) {
    __half2 h = *reinterpret_cast<__half2*>(&u);
    return __half22float2(h);
}
__device__ __forceinline__ unsigned hmul2(unsigned a, unsigned b) {
    __half2 r = __hmul2(*reinterpret_cast<__half2*>(&a), *reinterpret_cast<__half2*>(&b));
    return *reinterpret_cast<unsigned*>(&r);
}
__device__ __forceinline__ float lrelu(float x) { return fmaxf(x, 0.01f * x); }
__device__ __forceinline__ int swz(int x) { return (x * 16) ^ ((x & 8) << 1); }
__device__ __forceinline__ int bofs(int r, int x) { return r * 576 + swz(x); }

// ---- prep: row-reuse A-fragments (R15/R19 layout; no S2 table) ----
// ws[0..2559]    : conv1 frags, chunk c=(ty*2+txh), lane l:
//   row=l&15 (dx=row>>3, oc=row&7), tg=l>>4, tx=4*txh+tg, kx=tx-dx
//   elem pair d = ch (2d,2d+1): w1[oc][ch][ty][kx], 0 if oc>=6 or kx OOB
// ws[2560..5119] : conv2 frags from w2 (0 if oc>=5, ch>=6)
__global__ void pack_weights(const float* __restrict__ w1,
                             const float* __restrict__ w2,
                             unsigned* __restrict__ ws)
{
    int t = blockIdx.x * 256 + threadIdx.x;
    if (t < 640) {
        int c = t >> 6, l = t & 63;
        int row = l & 15, tg = l >> 4;
        int dx = row >> 3, oc = row & 7;
        int ty = c >> 1, tx = 4 * (c & 1) + tg, kx = tx - dx;
        unsigned q[4];
        #pragma unroll
        for (int d = 0; d < 4; ++d) {
            float v0 = 0.f, v1 = 0.f;
            if (oc < 6 && kx >= 0 && kx < 5) {
                v0 = w1[(oc * 8 + 2 * d) * 25 + ty * 5 + kx];
                v1 = w1[(oc * 8 + 2 * d + 1) * 25 + ty * 5 + kx];
            }
            q[d] = pk2(v0, v1);
        }
        *(uint4*)&ws[t * 4] = make_uint4(q[0], q[1], q[2], q[3]);
    } else if (t < 1280) {
        int u = t - 640;
        int c = u >> 6, l = u & 63;
        int row = l & 15, tg = l >> 4;
        int dx = row >> 3, oc = row & 7;
        int ty = c >> 1, tx = 4 * (c & 1) + tg, kx = tx - dx;
        unsigned q[4];
        #pragma unroll
        for (int d = 0; d < 4; ++d) {
            float v0 = 0.f, v1 = 0.f;
            if (oc < 5 && kx >= 0 && kx < 5) {
                if (2 * d < 6)     v0 = w2[(oc * 6 + 2 * d) * 25 + ty * 5 + kx];
                if (2 * d + 1 < 6) v1 = w2[(oc * 6 + 2 * d + 1) * 25 + ty * 5 + kx];
            }
            q[d] = pk2(v0, v1);
        }
        *(uint4*)&ws[2560 + u * 4] = make_uint4(q[0], q[1], q[2], q[3]);
    }
}

__global__ __launch_bounds__(256, 2)
void deq_kernel(const float* __restrict__ image,
                const unsigned* __restrict__ wks,
                const float* __restrict__ b1,
                const float* __restrict__ gam, const float* __restrict__ bet,
                const float* __restrict__ b2,
                const float* __restrict__ wh, const float* __restrict__ bh,
                float* __restrict__ out)
{
    __shared__ __align__(16) unsigned lds[NLDS];
    __shared__ float red[48];

    const int n    = blockIdx.x;
    const int tid  = threadIdx.x;
    const int lane = tid & 63;
    const int wid  = tid >> 6;          // wave owns output rows wid*8..+7
    const int col  = lane & 15;
    const int tg   = lane >> 4;
    const int dxl  = tg >> 1;
    const int sub  = tg & 1;

    for (int p = tid; p < NBUF; p += 256) lds[p] = 0u;
    for (int p = tid; p < 2560; p += 256) {
        lds[WL1_DW + p] = wks[p];
        lds[WL2_DW + p] = wks[2560 + p];
    }
    __syncthreads();

    {   // image -> zx bundle ch 5..7 + h-plane INDICATOR (ch6 = f16 1.0)
        const int yy = tid >> 3, xx0 = (tid & 7) << 2;
        float4 i0 = *(const float4*)&image[(n * 3 + 0) * 1024 + yy * 32 + xx0];
        float4 i1 = *(const float4*)&image[(n * 3 + 1) * 1024 + yy * 32 + xx0];
        float4 i2 = *(const float4*)&image[(n * 3 + 2) * 1024 + yy * 32 + xx0];
        float a0[4] = {i0.x, i0.y, i0.z, i0.w};
        float a1[4] = {i1.x, i1.y, i1.z, i1.w};
        float a2[4] = {i2.x, i2.y, i2.z, i2.w};
        #pragma unroll
        for (int i = 0; i < 4; ++i) {
            unsigned* bp = (unsigned*)((char*)lds + bofs(yy + 2, xx0 + 2 + i));
            bp[2] = pk2(0.f, a0[i]);
            bp[3] = pk2(a1[i], a2[i]);
            // indicator for the matching h-plane interior bundle (row+HOFF+2)
            unsigned* hp = (unsigned*)((char*)lds + bofs(yy + 2 + HOFF, xx0 + 2 + i));
            hp[3] = 0x00003C00u;     // pk2(1.0f16, 0)
        }
    }

    int sx2[2];
    #pragma unroll
    for (int txh = 0; txh < 2; ++txh)
        sx2[txh] = swz(2 * col + 4 * txh + tg);

    float b1q[4], b2q[4];
    #pragma unroll
    for (int r = 0; r < 4; ++r) {
        int oc = (tg * 4 + r) & 7;
        b1q[r] = (oc < 6) ? b1[oc] : 0.f;
        b2q[r] = (oc < 5) ? b2[oc] : 0.f;
    }
    const f32x4 ai1 = {b1q[0], b1q[1], b1q[2], b1q[3]};
    const f32x4 ai2 = {b2q[0], b2q[1], b2q[2], b2q[3]};

    __syncthreads();

    const int ay0 = wid << 3;
    const int hwB = bofs(0, 2 * col + dxl + 2);   // x-part of h/z write addr
    const int wlo = lane << 2;

    #pragma unroll 1
    for (int it = 0; it < 30; ++it) {
        // ========== conv1 (row-reuse: 24 B-reads, 80 MFMA; frags from LDS) ==========
        uint4 fw[10];
        #pragma unroll
        for (int c = 0; c < 10; ++c)
            fw[c] = *(const uint4*)&lds[WL1_DW + c * 256 + wlo];

        f32x4 acc[8];
        #pragma unroll
        for (int g = 0; g < 8; ++g) acc[g] = ai1;

        #pragma unroll
        for (int pr = 0; pr < 12; ++pr) {
            const char* rowp = (const char*)lds + (ay0 + pr) * 576;
            #pragma unroll
            for (int txh = 0; txh < 2; ++txh) {
                half8 pv = *(const half8*)(rowp + sx2[txh]);
                #pragma unroll
                for (int ty = 0; ty < 5; ++ty) {
                    const int g = pr - ty;
                    if (g >= 0 && g < 8)
                        acc[g] = __builtin_amdgcn_mfma_f32_16x16x32_f16(
                            __builtin_bit_cast(half8, fw[ty * 2 + txh]), pv, acc[g], 0, 0, 0);
                }
            }
        }

        // ---- leaky + UNNORMALIZED h write (pre-barrier!) + GN partial stats ----
        float ps_lo = 0.f, ps_hi = 0.f, pq_lo = 0.f, pq_hi = 0.f;
        #pragma unroll
        for (int g = 0; g < 8; ++g) {
            float h0 = lrelu(acc[g][0]), h1 = lrelu(acc[g][1]);
            float h2 = lrelu(acc[g][2]), h3 = lrelu(acc[g][3]);
            ps_lo += h0 + h1;  pq_lo = fmaf(h0, h0, fmaf(h1, h1, pq_lo));
            ps_hi += h2 + h3;  pq_hi = fmaf(h2, h2, fmaf(h3, h3, pq_hi));
            char* wp = (char*)lds + (ay0 + g + 2 + HOFF) * 576 + (hwB - 0 * 576);
            // NOTE: wp points at the bundle base of row (ay0+g+2+HOFF)
            wp = (char*)lds + bofs(ay0 + g + 2 + HOFF, 2 * col + dxl + 2);
            if (sub == 0) {                 // ch0-3: dwords 0,1
                *(uint2*)wp = make_uint2(pk2(h0, h1), pk2(h2, h3));
            } else {                        // ch4,5: dword 2 ONLY (keep indicator)
                *(unsigned*)(wp + 8) = pk2(h0, h1);
            }
        }

        // GN stats reduce: anchors (xor 1..8) then dx halves (xor 32)
        #pragma unroll
        for (int m = 1; m <= 8; m <<= 1) {
            ps_lo += __shfl_xor(ps_lo, m); ps_hi += __shfl_xor(ps_hi, m);
            pq_lo += __shfl_xor(pq_lo, m); pq_hi += __shfl_xor(pq_hi, m);
        }
        ps_lo += __shfl_xor(ps_lo, 32); ps_hi += __shfl_xor(ps_hi, 32);
        pq_lo += __shfl_xor(pq_lo, 32); pq_hi += __shfl_xor(pq_hi, 32);
        if (lane == 0)  { red[wid * 8 + 0] = ps_lo; red[wid * 8 + 1] = ps_hi;
                          red[wid * 8 + 4] = pq_lo; red[wid * 8 + 5] = pq_hi; }
        if (lane == 16) { red[wid * 8 + 2] = ps_lo; red[wid * 8 + 6] = pq_lo; }
        __syncthreads();                               // B1: h AND stats visible

        // ---- GN fold (all threads, all 6 channels) ----
        float scv[6], shv[6];
        #pragma unroll
        for (int g3 = 0; g3 < 3; ++g3) {
            float s = 0.f, q = 0.f;
            #pragma unroll
            for (int w = 0; w < 4; ++w) { s += red[w * 8 + g3]; q += red[w * 8 + 4 + g3]; }
            float mean = s * (1.f / 2048.f);
            float var  = q * (1.f / 2048.f) - mean * mean;
            float inv  = rsqrtf(var + 1e-5f);
            #pragma unroll
            for (int k = 0; k < 2; ++k) {
                int c = 2 * g3 + k;
                scv[c] = inv * gam[c];
                shv[c] = bet[c] - mean * scv[c];
            }
        }
        unsigned sp0 = pk2(scv[0], scv[1]), sp1 = pk2(scv[2], scv[3]), sp2 = pk2(scv[4], scv[5]);

        // ---- build conv2 frags: w2*sc + indicator weight padw = w2 . sh ----
        #pragma unroll
        for (int c = 0; c < 10; ++c) {
            uint4 wr = *(const uint4*)&lds[WL2_DW + c * 256 + wlo];
            float2 a = up2(wr.x), b = up2(wr.y), cc = up2(wr.z);
            float pw = fmaf(a.x, shv[0], fmaf(a.y, shv[1],
                       fmaf(b.x, shv[2], fmaf(b.y, shv[3],
                       fmaf(cc.x, shv[4], cc.y * shv[5])))));
            fw[c].x = hmul2(wr.x, sp0);
            fw[c].y = hmul2(wr.y, sp1);
            fw[c].z = hmul2(wr.z, sp2);
            fw[c].w = pk2(pw, 0.f);
        }

        // ========== conv2 (row-reuse over h plane; NO intervening barrier) ==========
        #pragma unroll
        for (int g = 0; g < 8; ++g) acc[g] = ai2;

        #pragma unroll
        for (int pr = 0; pr < 12; ++pr) {
            const char* rowp = (const char*)lds + (HOFF + ay0 + pr) * 576;
            #pragma unroll
            for (int txh = 0; txh < 2; ++txh) {
                half8 pv = *(const half8*)(rowp + sx2[txh]);
                #pragma unroll
                for (int ty = 0; ty < 5; ++ty) {
                    const int g = pr - ty;
                    if (g >= 0 && g < 8)
                        acc[g] = __builtin_amdgcn_mfma_f32_16x16x32_f16(
                            __builtin_bit_cast(half8, fw[ty * 2 + txh]), pv, acc[g], 0, 0, 0);
                }
            }
        }

        // ---- leaky + damped z RMW ----
        #pragma unroll
        for (int g = 0; g < 8; ++g) {
            char* zp = (char*)lds + bofs(ay0 + g + 2, 2 * col + dxl + 2);
            if (sub == 0) {
                uint2 zo = *(uint2*)zp;
                float2 za = up2(zo.x), zc = up2(zo.y);
                float z0 = 0.5f * za.x + 0.5f * lrelu(acc[g][0]);
                float z1 = 0.5f * za.y + 0.5f * lrelu(acc[g][1]);
                float z2 = 0.5f * zc.x + 0.5f * lrelu(acc[g][2]);
                float z3 = 0.5f * zc.y + 0.5f * lrelu(acc[g][3]);
                *(uint2*)zp = make_uint2(pk2(z0, z1), pk2(z2, z3));
            } else {
                _Float16* pz = (_Float16*)(zp + 8);
                float z4 = 0.5f * (float)pz[0] + 0.5f * lrelu(acc[g][0]);
                pz[0] = (_Float16)z4;
            }
        }
        __syncthreads();                               // B2: z visible for next iter
    }

    // ================= head: out[o] = <z, wh[o]> + bh[o] =================
    {
        const int yy = tid >> 3, xx0 = (tid & 7) << 2;
        float zf[5][4];
        #pragma unroll
        for (int i = 0; i < 4; ++i) {
            const unsigned* bp = (const unsigned*)((const char*)lds + bofs(yy + 2, xx0 + 2 + i));
            float2 f0 = up2(bp[0]), fb = up2(bp[1]), fc = up2(bp[2]);
            zf[0][i] = f0.x; zf[1][i] = f0.y; zf[2][i] = fb.x; zf[3][i] = fb.y; zf[4][i] = fc.x;
        }
        float ho[10];
        #pragma unroll
        for (int o = 0; o < 10; ++o) ho[o] = 0.f;
        #pragma unroll
        for (int c = 0; c < 5; ++c) {
            #pragma unroll
            for (int o = 0; o < 10; ++o) {
                float4 wv = *(const float4*)&wh[(o * 5 + c) * 1024 + yy * 32 + xx0];
                ho[o] = fmaf(zf[c][0], wv.x, ho[o]);
                ho[o] = fmaf(zf[c][1], wv.y, ho[o]);
                ho[o] = fmaf(zf[c][2], wv.z, ho[o]);
                ho[o] = fmaf(zf[c][3], wv.w, ho[o]);
            }
        }
        #pragma unroll
        for (int m = 1; m < 64; m <<= 1) {
            #pragma unroll
            for (int o = 0; o < 10; ++o) ho[o] += __shfl_xor(ho[o], m);
        }
        if (lane == 0) {
            #pragma unroll
            for (int o = 0; o < 10; ++o) red[wid * 10 + o] = ho[o];
        }
    }
    __syncthreads();
    if (tid < 10)
        out[n * 10 + tid] = red[tid] + red[10 + tid] + red[20 + tid] + red[30 + tid] + bh[tid];
}

extern "C" void kernel_launch(void* const* d_in, const int* in_sizes, int n_in,
                              void* d_out, int out_size, void* d_ws, size_t ws_size,
                              hipStream_t stream) {
    const float* image = (const float*)d_in[0];
    const float* w1    = (const float*)d_in[1];
    const float* b1    = (const float*)d_in[2];
    const float* gam   = (const float*)d_in[3];
    const float* bet   = (const float*)d_in[4];
    const float* w2    = (const float*)d_in[5];
    const float* b2    = (const float*)d_in[6];
    const float* wh    = (const float*)d_in[7];
    const float* bh    = (const float*)d_in[8];
    float* out = (float*)d_out;
    unsigned* ws = (unsigned*)d_ws;

    pack_weights<<<5, 256, 0, stream>>>(w1, w2, ws);

    const int N = in_sizes[0] / (3 * 32 * 32);   // 1024 images
    deq_kernel<<<N, 256, 0, stream>>>(image, ws, b1, gam, bet, b2, wh, bh, out);
}